// Round 5
// baseline (79.510 us; speedup 1.0000x reference)
//
#include <hip/hip_runtime.h>

// YOLO loss on (B,7,7,30) fp32 pred/target -> scalar.
// R5: split the loss into (a) per-cell part needing a gather (ch0..9: boxes,
// IoU, obj, conf) done via per-thread strided register loads, and (b) the cls
// part (ch10..29) which is elementwise in coalesced space: sum obj[c]*(P-T)^2
// computed from dwordx4 coalesced loads weighted by an LDS obj-mask.
// No staging LDS -> occupancy VGPR-limited (~24 waves/CU) instead of 5.

#define NC 30
#define CPB 256                  // cells per block == threads
#define TILE_DW (CPB * NC)       // 7680 dwords per tensor per tile

typedef float f4 __attribute__((ext_vector_type(4), aligned(4)));
typedef float f2 __attribute__((ext_vector_type(2), aligned(8)));

__device__ __forceinline__ float sq(float x) { return x * x; }

__device__ __forceinline__ void make_box(float cx, float cy, float w, float h,
                                         float jf, float kf, float b[4]) {
    float x = (cx + jf) * (1.0f / 7.0f);
    float y = (cy + kf) * (1.0f / 7.0f);
    b[0] = x - w * 0.5f;
    b[1] = y - h * 0.5f;
    b[2] = x + w * 0.5f;
    b[3] = y + h * 0.5f;
}

__device__ __forceinline__ float iou(const float a[4], const float b[4]) {
    float ix1 = fmaxf(a[0], b[0]);
    float iy1 = fmaxf(a[1], b[1]);
    float ix2 = fminf(a[2], b[2]);
    float iy2 = fminf(a[3], b[3]);
    float iw = fmaxf(ix2 - ix1, 0.0f);
    float ih = fmaxf(iy2 - iy1, 0.0f);
    float inter = iw * ih;
    float area_a = (a[2] - a[0]) * (a[3] - a[1]);
    float area_b = (b[2] - b[0]) * (b[3] - b[1]);
    return inter > 0.0f ? inter / (area_a + area_b - inter) : 0.0f;
}

// coord/conf part from ch0..9 only; returns partial loss, sets obj flag
__device__ __forceinline__ float coord_loss(const float P[10], const float T[10],
                                            float jf, float kf, bool* objp) {
    float b1[4], b2[4], tb[4];
    make_box(P[0], P[1], P[2], P[3], jf, kf, b1);
    make_box(P[5], P[6], P[7], P[8], jf, kf, b2);
    make_box(T[0], T[1], T[2], T[3], jf, kf, tb);

    float i1 = iou(b1, tb);
    float i2 = iou(b2, tb);

    bool obj = T[4] > 0.0f;
    bool pick1 = i1 >= i2;
    *objp = obj;

    float coo1 = 5.0f * (sq(P[0] - T[0]) + sq(P[1] - T[1]) +
                         sq(sqrtf(P[2]) - sqrtf(T[2])) +
                         sq(sqrtf(P[3]) - sqrtf(T[3]))) +
                 sq(P[4] - i1);
    float non1 = 0.5f * sq(P[4] - i2);

    float coo2 = 5.0f * (sq(P[5] - T[5]) + sq(P[6] - T[6]) +
                         sq(sqrtf(P[7]) - sqrtf(T[7])) +
                         sq(sqrtf(P[8]) - sqrtf(T[8]))) +
                 sq(P[9] - i2);
    float non2 = 0.5f * sq(P[9] - i1);

    float noobj = 0.5f * (P[4] * P[4] + P[9] * P[9]);

    float resp = pick1 ? (coo1 + non1) : (coo2 + non2);
    return obj ? resp : noobj;
}

__device__ __forceinline__ void load10(const float* row, float P[10]) {
    f2 a = *reinterpret_cast<const f2*>(row + 0);
    f2 b = *reinterpret_cast<const f2*>(row + 2);
    f2 c = *reinterpret_cast<const f2*>(row + 4);
    f2 d = *reinterpret_cast<const f2*>(row + 6);
    f2 e = *reinterpret_cast<const f2*>(row + 8);
    P[0] = a.x; P[1] = a.y; P[2] = b.x; P[3] = b.y; P[4] = c.x;
    P[5] = c.y; P[6] = d.x; P[7] = d.y; P[8] = e.x; P[9] = e.y;
}

template <bool USE_WS>
__global__ __launch_bounds__(CPB, 6) void yolo_partial_kernel(
    const float* __restrict__ pred, const float* __restrict__ targ,
    float* __restrict__ dst, int ncells, float scale) {
    __shared__ float maskv[CPB];
    __shared__ float wsum[CPB / 64];

    int t = threadIdx.x;
    int base = blockIdx.x * CPB;
    int cell = base + t;
    bool full_tile = (base + CPB) <= ncells;

    float acc = 0.0f;

    if (full_tile) {
        // ---- phase 1: per-cell coord/conf from ch0..9 (strided reg loads)
        {
            float P[10], T[10];
            load10(pred + (size_t)cell * NC, P);
            load10(targ + (size_t)cell * NC, T);
            int q7 = cell / 7;
            int kc = cell - q7 * 7;
            int jc = q7 % 7;
            bool obj;
            acc = coord_loss(P, T, (float)jc, (float)kc, &obj);
            maskv[t] = obj ? 1.0f : 0.0f;
        }
        __syncthreads();

        // ---- phase 2: coalesced masked cls sweep over the whole tile
        const float* pb = pred + (size_t)base * NC;
        const float* tb = targ + (size_t)base * NC;

#pragma unroll
        for (int i = 0; i < 7; ++i) {
            int idx = i * 1024 + 4 * t;  // dword index in tile, < 7168
            f4 p = *reinterpret_cast<const f4*>(pb + idx);
            f4 q = *reinterpret_cast<const f4*>(tb + idx);
            int c0 = idx / 30;
            int ch = idx - 30 * c0;
#pragma unroll
            for (int e = 0; e < 4; ++e) {
                int che = ch + e;
                int over = che >= 30;
                int ce = c0 + over;
                che -= 30 * over;
                float w = (che >= 10) ? maskv[ce] : 0.0f;
                float d = p[e] - q[e];
                acc += w * d * d;
            }
        }
        {
            int idx = 7168 + 2 * t;  // last 512 dwords as x2
            f2 p = *reinterpret_cast<const f2*>(pb + idx);
            f2 q = *reinterpret_cast<const f2*>(tb + idx);
            int c0 = idx / 30;
            int ch = idx - 30 * c0;
#pragma unroll
            for (int e = 0; e < 2; ++e) {
                int che = ch + e;
                int over = che >= 30;
                int ce = c0 + over;
                che -= 30 * over;
                float w = (che >= 10) ? maskv[ce] : 0.0f;
                float d = p[e] - q[e];
                acc += w * d * d;
            }
        }
    } else if (cell < ncells) {
        // tail block: fully scalar per-cell path (not hit for B=16384)
        float P[10], T[10];
        load10(pred + (size_t)cell * NC, P);
        load10(targ + (size_t)cell * NC, T);
        int q7 = cell / 7;
        bool obj;
        acc = coord_loss(P, T, (float)(q7 % 7), (float)(cell - q7 * 7), &obj);
        if (obj) {
            const float* pp = pred + (size_t)cell * NC;
            const float* tt = targ + (size_t)cell * NC;
            float cls = 0.0f;
#pragma unroll
            for (int e = 10; e < 30; ++e) {
                float d = pp[e] - tt[e];
                cls += d * d;
            }
            acc += cls;
        }
    }

    // ---- block reduction, one plain store
#pragma unroll
    for (int off = 32; off > 0; off >>= 1) acc += __shfl_down(acc, off);
    int wave = t >> 6;
    int lane = t & 63;
    if (lane == 0) wsum[wave] = acc;
    __syncthreads();

    if (t == 0) {
        float s = wsum[0] + wsum[1] + wsum[2] + wsum[3];
        if (USE_WS) {
            dst[blockIdx.x] = s * scale;
        } else {
            atomicAdd(dst, s * scale);
        }
    }
}

__global__ __launch_bounds__(1024) void reduce_kernel(
    const float* __restrict__ ws, float* __restrict__ out, int n) {
    float s = 0.0f;
    for (int i = threadIdx.x; i < n; i += 1024) s += ws[i];
#pragma unroll
    for (int off = 32; off > 0; off >>= 1) s += __shfl_down(s, off);

    __shared__ float acc[16];
    int wave = threadIdx.x >> 6;
    int lane = threadIdx.x & 63;
    if (lane == 0) acc[wave] = s;
    __syncthreads();

    if (threadIdx.x == 0) {
        float tot = 0.0f;
#pragma unroll
        for (int w = 0; w < 16; ++w) tot += acc[w];
        out[0] = tot;
    }
}

extern "C" void kernel_launch(void* const* d_in, const int* in_sizes, int n_in,
                              void* d_out, int out_size, void* d_ws, size_t ws_size,
                              hipStream_t stream) {
    const float* pred = (const float*)d_in[0];
    const float* targ = (const float*)d_in[1];
    float* out = (float*)d_out;

    int ncells = in_sizes[0] / NC;  // B*7*7
    int batch = ncells / 49;        // B
    float inv_b = 1.0f / (float)batch;

    int grid = (ncells + CPB - 1) / CPB;

    if (ws_size >= (size_t)grid * sizeof(float)) {
        float* ws = (float*)d_ws;
        yolo_partial_kernel<true><<<grid, CPB, 0, stream>>>(pred, targ, ws,
                                                            ncells, inv_b);
        reduce_kernel<<<1, 1024, 0, stream>>>(ws, out, grid);
    } else {
        hipMemsetAsync(out, 0, sizeof(float), stream);
        yolo_partial_kernel<false><<<grid, CPB, 0, stream>>>(pred, targ, out,
                                                             ncells, inv_b);
    }
}

// Round 6
// 54.168 us; speedup vs baseline: 1.4678x; 1.4678x over previous
//
#include <hip/hip_runtime.h>

// YOLO loss on (B,7,7,30) fp32 pred/target -> scalar.
// R6: single-pass fully-coalesced. 8 lanes per cell: lane j loads f4 at
// dword cell*30+4j (wave = 8 consecutive cells = contiguous 1KB per tensor).
// cls (ch10..29) computed elementwise in-lane, masked by T4 broadcast via
// shuffle. coord/IoU gathered into lane j=0 via 4 f4-shuffles (no LDS, no
// strided loads, no atomics, each byte read exactly once).

#define NC 30

typedef float f4 __attribute__((ext_vector_type(4), aligned(4)));

__device__ __forceinline__ float sq(float x) { return x * x; }

__device__ __forceinline__ void make_box(float cx, float cy, float w, float h,
                                         float jf, float kf, float b[4]) {
    float x = (cx + jf) * (1.0f / 7.0f);
    float y = (cy + kf) * (1.0f / 7.0f);
    b[0] = x - w * 0.5f;
    b[1] = y - h * 0.5f;
    b[2] = x + w * 0.5f;
    b[3] = y + h * 0.5f;
}

__device__ __forceinline__ float iou(const float a[4], const float b[4]) {
    float ix1 = fmaxf(a[0], b[0]);
    float iy1 = fmaxf(a[1], b[1]);
    float ix2 = fminf(a[2], b[2]);
    float iy2 = fminf(a[3], b[3]);
    float iw = fmaxf(ix2 - ix1, 0.0f);
    float ih = fmaxf(iy2 - iy1, 0.0f);
    float inter = iw * ih;
    float area_a = (a[2] - a[0]) * (a[3] - a[1]);
    float area_b = (b[2] - b[0]) * (b[3] - b[1]);
    return inter > 0.0f ? inter / (area_a + area_b - inter) : 0.0f;
}

template <bool USE_WS>
__global__ __launch_bounds__(256) void yolo_partial_kernel(
    const float* __restrict__ pred, const float* __restrict__ targ,
    float* __restrict__ dst, int ncells, float scale) {
    int t = threadIdx.x;
    int j = t & 7;            // lane within cell-group
    int gbase = t & ~7;       // first lane of this group (wave-relative ok:
                              // __shfl src is block-thread id within the wave)
    int nchunks = (ncells + 31) / 32;
    int total_dw = ncells * NC;

    float acc = 0.0f;

    for (int chunk = blockIdx.x; chunk < nchunks; chunk += gridDim.x) {
        int cell = chunk * 32 + (t >> 3);
        bool cell_ok = cell < ncells;

        int dwbase = cell * NC + 4 * j;  // nominal first dword for this lane
        // clamp for the very last group (lane j=7 of last cell overshoots by 2)
        int ldbase = dwbase;
        int shift = 0;
        if (cell_ok && dwbase + 4 > total_dw) {
            ldbase = total_dw - 4;
            shift = dwbase - ldbase;  // 2 for the final lane
        }

        f4 Pv = {0.f, 0.f, 0.f, 0.f}, Tv = {0.f, 0.f, 0.f, 0.f};
        if (cell_ok) {
            Pv = *reinterpret_cast<const f4*>(pred + ldbase);
            Tv = *reinterpret_cast<const f4*>(targ + ldbase);
        }
        // undo clamp: put elements back at nominal channel positions;
        // elements with actual-dword < nominal base are owned by lane j-1.
        if (shift) {
            f4 p2 = Pv, t2 = Tv;
#pragma unroll
            for (int e = 0; e < 4; ++e) {
                int src = e + shift;  // nominal elem e = loaded elem e+shift
                p2[e] = (src < 4) ? Pv[src] : 0.f;
                t2[e] = (src < 4) ? Tv[src] : 0.f;
            }
            Pv = p2;
            Tv = t2;
        }

        // broadcast T4 (lane j=1, elem 0) to the whole group
        float t4 = __shfl(Tv[0], gbase + 1, 64);
        float objw = t4 > 0.0f ? 1.0f : 0.0f;

        // cls: channels 10..29 -> 4j+e in [10,29]
        float cls = 0.0f;
#pragma unroll
        for (int e = 0; e < 4; ++e) {
            int ch = 4 * j + e;
            float d = Pv[e] - Tv[e];
            cls += (ch >= 10 && ch < 30) ? d * d : 0.0f;
        }
        acc += objw * cls;

        // gather d4..7 (from j=1) and d8..11 (from j=2) for both tensors
        float s1p[4], s2p[4], s1t[4], s2t[4];
#pragma unroll
        for (int e = 0; e < 4; ++e) {
            s1p[e] = __shfl(Pv[e], gbase + 1, 64);
            s2p[e] = __shfl(Pv[e], gbase + 2, 64);
            s1t[e] = __shfl(Tv[e], gbase + 1, 64);
            s2t[e] = __shfl(Tv[e], gbase + 2, 64);
        }

        if (j == 0 && cell_ok) {
            // lane0 owns d0..3; s1*=d4..7; s2*=d8..11
            float P0 = Pv[0], P1 = Pv[1], P2 = Pv[2], P3 = Pv[3];
            float P4 = s1p[0], P5 = s1p[1], P6 = s1p[2], P7 = s1p[3];
            float P8 = s2p[0], P9 = s2p[1];
            float T0 = Tv[0], T1 = Tv[1], T2 = Tv[2], T3 = Tv[3];
            float T4 = s1t[0], T5 = s1t[1], T6 = s1t[2], T7 = s1t[3];
            float T8 = s2t[0];

            int q7 = cell / 7;
            float kf = (float)(cell - q7 * 7);
            float jf = (float)(q7 % 7);

            float b1[4], b2[4], tb[4];
            make_box(P0, P1, P2, P3, jf, kf, b1);
            make_box(P5, P6, P7, P8, jf, kf, b2);
            make_box(T0, T1, T2, T3, jf, kf, tb);

            float i1 = iou(b1, tb);
            float i2 = iou(b2, tb);

            bool obj = T4 > 0.0f;
            bool pick1 = i1 >= i2;

            float coo1 = 5.0f * (sq(P0 - T0) + sq(P1 - T1) +
                                 sq(sqrtf(P2) - sqrtf(T2)) +
                                 sq(sqrtf(P3) - sqrtf(T3))) +
                         sq(P4 - i1);
            float non1 = 0.5f * sq(P4 - i2);

            float coo2 = 5.0f * (sq(P5 - T5) + sq(P6 - T6) +
                                 sq(sqrtf(P7) - sqrtf(T7)) +
                                 sq(sqrtf(P8) - sqrtf(T8))) +
                         sq(P9 - i2);
            float non2 = 0.5f * sq(P9 - i1);

            float noobj = 0.5f * (P4 * P4 + P9 * P9);

            float resp = pick1 ? (coo1 + non1) : (coo2 + non2);
            acc += obj ? resp : noobj;
        }
    }

    // block reduction, one plain store
#pragma unroll
    for (int off = 32; off > 0; off >>= 1) acc += __shfl_down(acc, off);

    __shared__ float wsum[4];
    int wave = t >> 6;
    int lane = t & 63;
    if (lane == 0) wsum[wave] = acc;
    __syncthreads();

    if (t == 0) {
        float s = wsum[0] + wsum[1] + wsum[2] + wsum[3];
        if (USE_WS) {
            dst[blockIdx.x] = s * scale;
        } else {
            atomicAdd(dst, s * scale);
        }
    }
}

__global__ __launch_bounds__(1024) void reduce_kernel(
    const float* __restrict__ ws, float* __restrict__ out, int n) {
    float s = 0.0f;
    for (int i = threadIdx.x; i < n; i += 1024) s += ws[i];
#pragma unroll
    for (int off = 32; off > 0; off >>= 1) s += __shfl_down(s, off);

    __shared__ float acc[16];
    int wave = threadIdx.x >> 6;
    int lane = threadIdx.x & 63;
    if (lane == 0) acc[wave] = s;
    __syncthreads();

    if (threadIdx.x == 0) {
        float tot = 0.0f;
#pragma unroll
        for (int w = 0; w < 16; ++w) tot += acc[w];
        out[0] = tot;
    }
}

extern "C" void kernel_launch(void* const* d_in, const int* in_sizes, int n_in,
                              void* d_out, int out_size, void* d_ws, size_t ws_size,
                              hipStream_t stream) {
    const float* pred = (const float*)d_in[0];
    const float* targ = (const float*)d_in[1];
    float* out = (float*)d_out;

    int ncells = in_sizes[0] / NC;  // B*7*7
    int batch = ncells / 49;        // B
    float inv_b = 1.0f / (float)batch;

    int nchunks = (ncells + 31) / 32;
    int grid = nchunks < 2048 ? nchunks : 2048;

    if (ws_size >= (size_t)grid * sizeof(float)) {
        float* ws = (float*)d_ws;
        yolo_partial_kernel<true><<<grid, 256, 0, stream>>>(pred, targ, ws,
                                                            ncells, inv_b);
        reduce_kernel<<<1, 1024, 0, stream>>>(ws, out, grid);
    } else {
        hipMemsetAsync(out, 0, sizeof(float), stream);
        yolo_partial_kernel<false><<<grid, 256, 0, stream>>>(pred, targ, out,
                                                             ncells, inv_b);
    }
}

// Round 7
// 37.880 us; speedup vs baseline: 2.0990x; 1.4300x over previous
//
#include <hip/hip_runtime.h>

// YOLO loss on (B,7,7,30) fp32 pred/target -> scalar.
// R7: single-pass coalesced like R6, but 4 lanes/cell (f8 each) instead of
// 8 lanes/cell (f4). cls is computed fully in-lane (static channel mask, no
// gather); only 4 shuffles/iter (T4 bcast + P8,P9,T8; T9 unused by ref);
// coord/IoU divergent section runs on 16/64 lanes. R6 was VALU-bound
// (65% VALUBusy, L3-resident replays at 80us) from 17 bpermutes + 1/8-duty
// divergence per 8 cells.

#define NC 30

typedef float f4 __attribute__((ext_vector_type(4), aligned(4)));

__device__ __forceinline__ float sq(float x) { return x * x; }

__device__ __forceinline__ void make_box(float cx, float cy, float w, float h,
                                         float jf, float kf, float b[4]) {
    float x = (cx + jf) * (1.0f / 7.0f);
    float y = (cy + kf) * (1.0f / 7.0f);
    b[0] = x - w * 0.5f;
    b[1] = y - h * 0.5f;
    b[2] = x + w * 0.5f;
    b[3] = y + h * 0.5f;
}

__device__ __forceinline__ float iou(const float a[4], const float b[4]) {
    float ix1 = fmaxf(a[0], b[0]);
    float iy1 = fmaxf(a[1], b[1]);
    float ix2 = fminf(a[2], b[2]);
    float iy2 = fminf(a[3], b[3]);
    float iw = fmaxf(ix2 - ix1, 0.0f);
    float ih = fmaxf(iy2 - iy1, 0.0f);
    float inter = iw * ih;
    float area_a = (a[2] - a[0]) * (a[3] - a[1]);
    float area_b = (b[2] - b[0]) * (b[3] - b[1]);
    return inter > 0.0f ? inter / (area_a + area_b - inter) : 0.0f;
}

template <bool USE_WS>
__global__ __launch_bounds__(256) void yolo_partial_kernel(
    const float* __restrict__ pred, const float* __restrict__ targ,
    float* __restrict__ dst, int ncells, float scale) {
    int t = threadIdx.x;
    int q = t & 3;        // lane within 4-lane cell-group
    int gbase = t & ~3;   // group leader (mod-64 semantics of __shfl are fine)
    int nchunks = (ncells + 63) / 64;  // 64 cells per block-iteration
    int total_dw = ncells * NC;

    float acc = 0.0f;

    for (int chunk = blockIdx.x; chunk < nchunks; chunk += gridDim.x) {
        int cell = chunk * 64 + (t >> 2);
        bool ok = cell < ncells;

        // lane q owns dwords [cell*30 + 8q, +8) of both tensors
        int dwbase = cell * NC + 8 * q;
        int ldbase = dwbase;
        int shift = 0;
        if (ok && dwbase + 8 > total_dw) {  // only the global last lane
            ldbase = total_dw - 8;
            shift = dwbase - ldbase;  // == 2
        }

        f4 Pa = {0.f, 0.f, 0.f, 0.f}, Pb = {0.f, 0.f, 0.f, 0.f};
        f4 Ta = {0.f, 0.f, 0.f, 0.f}, Tb = {0.f, 0.f, 0.f, 0.f};
        if (ok) {
            Pa = *reinterpret_cast<const f4*>(pred + ldbase);
            Pb = *reinterpret_cast<const f4*>(pred + ldbase + 4);
            Ta = *reinterpret_cast<const f4*>(targ + ldbase);
            Tb = *reinterpret_cast<const f4*>(targ + ldbase + 4);
        }
        if (shift) {  // remap loaded -> nominal channel positions (shift==2)
            f4 p0 = Pa, p1 = Pb, u0 = Ta, u1 = Tb;
            Pa[0] = p0[2]; Pa[1] = p0[3]; Pa[2] = p1[0]; Pa[3] = p1[1];
            Pb[0] = p1[2]; Pb[1] = p1[3]; Pb[2] = 0.f;   Pb[3] = 0.f;
            Ta[0] = u0[2]; Ta[1] = u0[3]; Ta[2] = u1[0]; Ta[3] = u1[1];
            Tb[0] = u1[2]; Tb[1] = u1[3]; Tb[2] = 0.f;   Tb[3] = 0.f;
        }

        // obj mask: T4 lives in group-leader's Tb[0]
        float t4 = __shfl(Tb[0], gbase, 64);
        float objw = t4 > 0.0f ? 1.0f : 0.0f;

        // cls partial fully in-lane: ch = 8q + e (Pa: e=0..3, Pb: e=4..7)
        float cls = 0.0f;
#pragma unroll
        for (int e = 0; e < 4; ++e) {
            int ch = 8 * q + e;
            float d = Pa[e] - Ta[e];
            cls += (ch >= 10 && ch < NC) ? d * d : 0.0f;
        }
#pragma unroll
        for (int e = 0; e < 4; ++e) {
            int ch = 8 * q + 4 + e;
            float d = Pb[e] - Tb[e];
            cls += (ch >= 10 && ch < NC) ? d * d : 0.0f;
        }
        acc += objw * cls;

        // gather for coord: lane q=1 holds d8..11 in its Pa/Ta
        float P8 = __shfl(Pa[0], gbase + 1, 64);
        float P9 = __shfl(Pa[1], gbase + 1, 64);
        float T8 = __shfl(Ta[0], gbase + 1, 64);  // T9 unused by reference

        if (q == 0 && ok) {
            // local: P0..3=Pa, P4..7=Pb, T0..3=Ta, T4..7=Tb
            int q7 = cell / 7;
            float kf = (float)(cell - q7 * 7);
            float jf = (float)(q7 % 7);

            float b1[4], b2[4], tbx[4];
            make_box(Pa[0], Pa[1], Pa[2], Pa[3], jf, kf, b1);
            make_box(Pb[1], Pb[2], Pb[3], P8, jf, kf, b2);
            make_box(Ta[0], Ta[1], Ta[2], Ta[3], jf, kf, tbx);

            float i1 = iou(b1, tbx);
            float i2 = iou(b2, tbx);

            bool obj = Tb[0] > 0.0f;
            bool pick1 = i1 >= i2;

            float coo1 = 5.0f * (sq(Pa[0] - Ta[0]) + sq(Pa[1] - Ta[1]) +
                                 sq(sqrtf(Pa[2]) - sqrtf(Ta[2])) +
                                 sq(sqrtf(Pa[3]) - sqrtf(Ta[3]))) +
                         sq(Pb[0] - i1);
            float non1 = 0.5f * sq(Pb[0] - i2);

            float coo2 = 5.0f * (sq(Pb[1] - Tb[1]) + sq(Pb[2] - Tb[2]) +
                                 sq(sqrtf(Pb[3]) - sqrtf(Tb[3])) +
                                 sq(sqrtf(P8) - sqrtf(T8))) +
                         sq(P9 - i2);
            float non2 = 0.5f * sq(P9 - i1);

            float noobj = 0.5f * (Pb[0] * Pb[0] + P9 * P9);

            float resp = pick1 ? (coo1 + non1) : (coo2 + non2);
            acc += obj ? resp : noobj;
        }
    }

    // block reduction, one plain store per block
#pragma unroll
    for (int off = 32; off > 0; off >>= 1) acc += __shfl_down(acc, off);

    __shared__ float wsum[4];
    int wave = t >> 6;
    int lane = t & 63;
    if (lane == 0) wsum[wave] = acc;
    __syncthreads();

    if (t == 0) {
        float s = wsum[0] + wsum[1] + wsum[2] + wsum[3];
        if (USE_WS) {
            dst[blockIdx.x] = s * scale;
        } else {
            atomicAdd(dst, s * scale);
        }
    }
}

__global__ __launch_bounds__(1024) void reduce_kernel(
    const float* __restrict__ ws, float* __restrict__ out, int n) {
    float s = 0.0f;
    for (int i = threadIdx.x; i < n; i += 1024) s += ws[i];
#pragma unroll
    for (int off = 32; off > 0; off >>= 1) s += __shfl_down(s, off);

    __shared__ float acc[16];
    int wave = threadIdx.x >> 6;
    int lane = threadIdx.x & 63;
    if (lane == 0) acc[wave] = s;
    __syncthreads();

    if (threadIdx.x == 0) {
        float tot = 0.0f;
#pragma unroll
        for (int w = 0; w < 16; ++w) tot += acc[w];
        out[0] = tot;
    }
}

extern "C" void kernel_launch(void* const* d_in, const int* in_sizes, int n_in,
                              void* d_out, int out_size, void* d_ws, size_t ws_size,
                              hipStream_t stream) {
    const float* pred = (const float*)d_in[0];
    const float* targ = (const float*)d_in[1];
    float* out = (float*)d_out;

    int ncells = in_sizes[0] / NC;  // B*7*7
    int batch = ncells / 49;        // B
    float inv_b = 1.0f / (float)batch;

    int nchunks = (ncells + 63) / 64;
    int grid = nchunks < 2048 ? nchunks : 2048;

    if (ws_size >= (size_t)grid * sizeof(float)) {
        float* ws = (float*)d_ws;
        yolo_partial_kernel<true><<<grid, 256, 0, stream>>>(pred, targ, ws,
                                                            ncells, inv_b);
        reduce_kernel<<<1, 1024, 0, stream>>>(ws, out, grid);
    } else {
        hipMemsetAsync(out, 0, sizeof(float), stream);
        yolo_partial_kernel<false><<<grid, 256, 0, stream>>>(pred, targ, out,
                                                             ncells, inv_b);
    }
}